// Round 1
// baseline (207.166 us; speedup 1.0000x reference)
//
#include <hip/hip_runtime.h>
#include <hip/hip_bf16.h>

// Sizes from the reference
#define BATCH   128
#define SEQ_T   64
#define SEQ_A   1024
#define SEQ_V   512
#define D_T     768
#define D_AV    256
#define DST_LEN 64

// ---------------------------------------------------------------------------
// Kernel 1: straight float4 copy for text passthrough
// ---------------------------------------------------------------------------
__global__ void copy_f4_kernel(const float4* __restrict__ in,
                               float4* __restrict__ out, int n4) {
    int i = blockIdx.x * blockDim.x + threadIdx.x;
    if (i < n4) out[i] = in[i];
}

// ---------------------------------------------------------------------------
// Kernel 2: segment-mean pooling ("align")
//   grid.x  = BATCH * (DST_LEN/4)   (each block: one b, four output rows j)
//   block   = 256 threads: wave w (tid>>6) owns row j = jgrp*4 + w,
//             lane (tid&63) owns float4 column chunk of D=256 (64 chunks)
//   out[b][j][:] = (1<=j<=min_len) ? sum_{t=(j-1)ps}^{min(j*ps,len)-1} x[b][t][:] / ps : 0
// ---------------------------------------------------------------------------
__global__ void align_kernel(const float* __restrict__ x,
                             const int* __restrict__ text_len,
                             const int* __restrict__ lengths,
                             float* __restrict__ out,
                             int T) {
    const int blk  = blockIdx.x;
    const int b    = blk >> 4;        // DST_LEN/4 == 16 row-groups per sample
    const int jgrp = blk & 15;
    const int tid  = threadIdx.x;
    const int jj   = tid >> 6;        // wave index 0..3 -> row within group
    const int lane = tid & 63;        // float4 column chunk 0..63 (D/4 == 64)
    const int j    = jgrp * 4 + jj;

    const int ml  = text_len[b] - 2;  // min_len, in [1, 63]
    const int len = lengths[b];

    float4 acc = make_float4(0.f, 0.f, 0.f, 0.f);
    if (j >= 1 && j <= ml) {
        const int ps = (len + ml - 1) / ml;
        const int lo = (j - 1) * ps;
        int hi = j * ps;
        if (hi > len) hi = len;
        const float4* __restrict__ xrow =
            (const float4*)(x + (size_t)b * (size_t)T * D_AV);
        for (int t = lo; t < hi; ++t) {
            float4 v = xrow[(size_t)t * (D_AV / 4) + lane];
            acc.x += v.x; acc.y += v.y; acc.z += v.z; acc.w += v.w;
        }
        const float inv = 1.0f / (float)ps;
        acc.x *= inv; acc.y *= inv; acc.z *= inv; acc.w *= inv;
    }
    float4* __restrict__ orow =
        (float4*)(out + ((size_t)b * DST_LEN + j) * D_AV);
    orow[lane] = acc;   // rows outside [1, min_len] get explicit zeros
}

extern "C" void kernel_launch(void* const* d_in, const int* in_sizes, int n_in,
                              void* d_out, int out_size, void* d_ws, size_t ws_size,
                              hipStream_t stream) {
    const float* text_x  = (const float*)d_in[0];
    const float* audio_x = (const float*)d_in[1];
    const float* video_x = (const float*)d_in[2];
    const int* text_lengths  = (const int*)d_in[3];
    const int* audio_lengths = (const int*)d_in[4];
    const int* video_lengths = (const int*)d_in[5];

    float* out = (float*)d_out;
    float* out_text  = out;                                        // B*64*768
    float* out_audio = out_text  + (size_t)BATCH * SEQ_T * D_T;    // B*64*256
    float* out_video = out_audio + (size_t)BATCH * DST_LEN * D_AV; // B*64*256

    // 1) text passthrough
    {
        const int n4 = (BATCH * SEQ_T * D_T) / 4;   // 1,572,864
        const int blocks = (n4 + 255) / 256;
        copy_f4_kernel<<<blocks, 256, 0, stream>>>(
            (const float4*)text_x, (float4*)out_text, n4);
    }

    // 2) audio align
    {
        const int blocks = BATCH * (DST_LEN / 4);   // 2048
        align_kernel<<<blocks, 256, 0, stream>>>(
            audio_x, text_lengths, audio_lengths, out_audio, SEQ_A);
    }

    // 3) video align
    {
        const int blocks = BATCH * (DST_LEN / 4);   // 2048
        align_kernel<<<blocks, 256, 0, stream>>>(
            video_x, text_lengths, video_lengths, out_video, SEQ_V);
    }
}

// Round 2
// 98.483 us; speedup vs baseline: 2.1036x; 2.1036x over previous
//
#include <hip/hip_runtime.h>
#include <hip/hip_bf16.h>

// Sizes from the reference
#define BATCH   128
#define SEQ_T   64
#define SEQ_A   1024
#define SEQ_V   512
#define D_T     768
#define D_AV    256
#define DST_LEN 64

// ---------------------------------------------------------------------------
// Kernel 1: straight float4 copy for text passthrough
// ---------------------------------------------------------------------------
__global__ void copy_f4_kernel(const float4* __restrict__ in,
                               float4* __restrict__ out, int n4) {
    int i = blockIdx.x * blockDim.x + threadIdx.x;
    if (i < n4) out[i] = in[i];
}

// ---------------------------------------------------------------------------
// Kernel 2: input-row-parallel segment-mean pooling ("align"), atomic flush.
//   One wave = 8 consecutive input rows of one sample.
//   lane (tid&63) owns float4 column chunk (D=256 -> 64 chunks, full row/wave).
//   Row t (< len) contributes x[b][t][:] / ps to out[b][t/ps + 1][:].
//   Runs of rows sharing the same output row are accumulated in registers and
//   flushed with 4 atomicAdds per lane at window boundaries.
//   Requires out pre-zeroed (hipMemsetAsync in kernel_launch).
// ---------------------------------------------------------------------------
__global__ void accum_align_kernel(const float* __restrict__ x,
                                   const int* __restrict__ text_len,
                                   const int* __restrict__ lengths,
                                   float* __restrict__ out,
                                   int T) {
    const int chunks = T >> 5;                 // 32 rows per block (4 waves x 8)
    const int b    = blockIdx.x / chunks;
    const int c    = blockIdx.x % chunks;
    const int wave = threadIdx.x >> 6;
    const int lane = threadIdx.x & 63;
    const int t0   = c * 32 + wave * 8;

    const int len = lengths[b];
    if (t0 >= len) return;                     // wave-uniform early exit

    const int ml = text_len[b] - 2;            // min_len in [1, 63]
    const unsigned ps = ((unsigned)(len + ml - 1)) / (unsigned)ml;
    const float inv = 1.0f / (float)ps;

    const float4* __restrict__ xrow =
        (const float4*)(x + (size_t)b * (size_t)T * D_AV);
    float* __restrict__ outb = out + (size_t)b * DST_LEN * D_AV;

    float4 acc = make_float4(0.f, 0.f, 0.f, 0.f);
    int jcur = -1;
    const int tend = (t0 + 8 < len) ? (t0 + 8) : len;
    for (int t = t0; t < tend; ++t) {
        const int j = (int)((unsigned)t / ps) + 1;   // 1 <= j <= ml
        if (j != jcur) {
            if (jcur > 0) {
                float* dst = outb + (size_t)jcur * D_AV + lane * 4;
                atomicAdd(dst + 0, acc.x * inv);
                atomicAdd(dst + 1, acc.y * inv);
                atomicAdd(dst + 2, acc.z * inv);
                atomicAdd(dst + 3, acc.w * inv);
            }
            acc = make_float4(0.f, 0.f, 0.f, 0.f);
            jcur = j;
        }
        float4 v = xrow[(size_t)t * (D_AV / 4) + lane];
        acc.x += v.x; acc.y += v.y; acc.z += v.z; acc.w += v.w;
    }
    {
        float* dst = outb + (size_t)jcur * D_AV + lane * 4;
        atomicAdd(dst + 0, acc.x * inv);
        atomicAdd(dst + 1, acc.y * inv);
        atomicAdd(dst + 2, acc.z * inv);
        atomicAdd(dst + 3, acc.w * inv);
    }
}

extern "C" void kernel_launch(void* const* d_in, const int* in_sizes, int n_in,
                              void* d_out, int out_size, void* d_ws, size_t ws_size,
                              hipStream_t stream) {
    const float* text_x  = (const float*)d_in[0];
    const float* audio_x = (const float*)d_in[1];
    const float* video_x = (const float*)d_in[2];
    const int* text_lengths  = (const int*)d_in[3];
    const int* audio_lengths = (const int*)d_in[4];
    const int* video_lengths = (const int*)d_in[5];

    float* out = (float*)d_out;
    float* out_text  = out;                                        // B*64*768
    float* out_audio = out_text  + (size_t)BATCH * SEQ_T * D_T;    // B*64*256
    float* out_video = out_audio + (size_t)BATCH * DST_LEN * D_AV; // B*64*256

    // 0) zero the audio+video output regions (adjacent) for atomic accumulate
    hipMemsetAsync(out_audio, 0,
                   (size_t)2 * BATCH * DST_LEN * D_AV * sizeof(float), stream);

    // 1) text passthrough
    {
        const int n4 = (BATCH * SEQ_T * D_T) / 4;   // 1,572,864
        const int blocks = (n4 + 255) / 256;
        copy_f4_kernel<<<blocks, 256, 0, stream>>>(
            (const float4*)text_x, (float4*)out_text, n4);
    }

    // 2) audio align: 128 * (1024/32) = 4096 blocks
    accum_align_kernel<<<BATCH * (SEQ_A / 32), 256, 0, stream>>>(
        audio_x, text_lengths, audio_lengths, out_audio, SEQ_A);

    // 3) video align: 128 * (512/32) = 2048 blocks
    accum_align_kernel<<<BATCH * (SEQ_V / 32), 256, 0, stream>>>(
        video_x, text_lengths, video_lengths, out_video, SEQ_V);
}

// Round 3
// 93.378 us; speedup vs baseline: 2.2186x; 1.0547x over previous
//
#include <hip/hip_runtime.h>
#include <hip/hip_bf16.h>

// Sizes from the reference
#define BATCH   128
#define SEQ_T   64
#define SEQ_A   1024
#define SEQ_V   512
#define D_T     768
#define D_AV    256
#define DST_LEN 64

// ---------------------------------------------------------------------------
// Kernel 1: text passthrough copy + zero-init of audio/video output region.
//   i < n_copy4          : out_text[i] = in[i]
//   n_copy4 <= i < +n_z4 : out_av[i - n_copy4] = 0
// (replaces hipMemsetAsync, whose rocclr fill kernel cost ~75 us/replay)
// ---------------------------------------------------------------------------
__global__ void copy_and_zero_kernel(const float4* __restrict__ in,
                                     float4* __restrict__ out_text,
                                     float4* __restrict__ out_av,
                                     int n_copy4, int n_zero4) {
    int i = blockIdx.x * blockDim.x + threadIdx.x;
    if (i < n_copy4) {
        out_text[i] = in[i];
    } else {
        int k = i - n_copy4;
        if (k < n_zero4)
            out_av[k] = make_float4(0.f, 0.f, 0.f, 0.f);
    }
}

// ---------------------------------------------------------------------------
// Kernel 2: input-row-parallel segment-mean pooling ("align"), atomic flush.
//   One wave = 8 consecutive input rows of one sample.
//   lane (tid&63) owns float4 column chunk (D=256 -> 64 chunks, full row/wave).
//   Row t (< len) contributes x[b][t][:] / ps to out[b][t/ps + 1][:].
//   Runs of rows sharing the same output row accumulate in registers and
//   flush with 4 atomicAdds per lane at window boundaries.
//   Requires out pre-zeroed (done by copy_and_zero_kernel, same stream).
// ---------------------------------------------------------------------------
__global__ void accum_align_kernel(const float* __restrict__ x,
                                   const int* __restrict__ text_len,
                                   const int* __restrict__ lengths,
                                   float* __restrict__ out,
                                   int T) {
    const int chunks = T >> 5;                 // 32 rows per block (4 waves x 8)
    const int b    = blockIdx.x / chunks;
    const int c    = blockIdx.x % chunks;
    const int wave = threadIdx.x >> 6;
    const int lane = threadIdx.x & 63;
    const int t0   = c * 32 + wave * 8;

    const int len = lengths[b];
    if (t0 >= len) return;                     // wave-uniform early exit

    const int ml = text_len[b] - 2;            // min_len in [1, 63]
    const unsigned ps = ((unsigned)(len + ml - 1)) / (unsigned)ml;
    const float inv = 1.0f / (float)ps;

    const float4* __restrict__ xrow =
        (const float4*)(x + (size_t)b * (size_t)T * D_AV);
    float* __restrict__ outb = out + (size_t)b * DST_LEN * D_AV;

    float4 acc = make_float4(0.f, 0.f, 0.f, 0.f);
    int jcur = -1;
    const int tend = (t0 + 8 < len) ? (t0 + 8) : len;
    for (int t = t0; t < tend; ++t) {
        const int j = (int)((unsigned)t / ps) + 1;   // 1 <= j <= ml
        if (j != jcur) {
            if (jcur > 0) {
                float* dst = outb + (size_t)jcur * D_AV + lane * 4;
                atomicAdd(dst + 0, acc.x * inv);
                atomicAdd(dst + 1, acc.y * inv);
                atomicAdd(dst + 2, acc.z * inv);
                atomicAdd(dst + 3, acc.w * inv);
            }
            acc = make_float4(0.f, 0.f, 0.f, 0.f);
            jcur = j;
        }
        float4 v = xrow[(size_t)t * (D_AV / 4) + lane];
        acc.x += v.x; acc.y += v.y; acc.z += v.z; acc.w += v.w;
    }
    {
        float* dst = outb + (size_t)jcur * D_AV + lane * 4;
        atomicAdd(dst + 0, acc.x * inv);
        atomicAdd(dst + 1, acc.y * inv);
        atomicAdd(dst + 2, acc.z * inv);
        atomicAdd(dst + 3, acc.w * inv);
    }
}

extern "C" void kernel_launch(void* const* d_in, const int* in_sizes, int n_in,
                              void* d_out, int out_size, void* d_ws, size_t ws_size,
                              hipStream_t stream) {
    const float* text_x  = (const float*)d_in[0];
    const float* audio_x = (const float*)d_in[1];
    const float* video_x = (const float*)d_in[2];
    const int* text_lengths  = (const int*)d_in[3];
    const int* audio_lengths = (const int*)d_in[4];
    const int* video_lengths = (const int*)d_in[5];

    float* out = (float*)d_out;
    float* out_text  = out;                                        // B*64*768
    float* out_audio = out_text  + (size_t)BATCH * SEQ_T * D_T;    // B*64*256
    float* out_video = out_audio + (size_t)BATCH * DST_LEN * D_AV; // B*64*256

    // 1) text passthrough + zero audio/video output region (adjacent)
    {
        const int n_copy4 = (BATCH * SEQ_T * D_T) / 4;             // 1,572,864
        const int n_zero4 = (2 * BATCH * DST_LEN * D_AV) / 4;      // 1,048,576
        const int total   = n_copy4 + n_zero4;
        const int blocks  = (total + 255) / 256;                   // 10,240
        copy_and_zero_kernel<<<blocks, 256, 0, stream>>>(
            (const float4*)text_x, (float4*)out_text, (float4*)out_audio,
            n_copy4, n_zero4);
    }

    // 2) audio align: 128 * (1024/32) = 4096 blocks
    accum_align_kernel<<<BATCH * (SEQ_A / 32), 256, 0, stream>>>(
        audio_x, text_lengths, audio_lengths, out_audio, SEQ_A);

    // 3) video align: 128 * (512/32) = 2048 blocks
    accum_align_kernel<<<BATCH * (SEQ_V / 32), 256, 0, stream>>>(
        video_x, text_lengths, video_lengths, out_video, SEQ_V);
}

// Round 4
// 35.048 us; speedup vs baseline: 5.9109x; 2.6643x over previous
//
#include <hip/hip_runtime.h>
#include <hip/hip_bf16.h>

// Sizes from the reference
#define BATCH   128
#define SEQ_T   64
#define SEQ_A   1024
#define SEQ_V   512
#define D_T     768
#define D_AV    256
#define DST_LEN 64

// Grid layout (all 256-thread blocks, single fused kernel):
//   [0, NB_COPY)                : text passthrough, 4 float4 per thread
//   [NB_COPY, +8192)            : audio align, one block per (b, j)
//   [NB_COPY+8192, +8192)       : video align, one block per (b, j)
#define NB_COPY 1536   // 1,572,864 float4 / (256 thr * 4 f4)

__device__ __forceinline__ void align_row(const float* __restrict__ x,
                                          const int* __restrict__ text_len,
                                          const int* __restrict__ lengths,
                                          float* __restrict__ out,
                                          int T, int idx) {
    const int b    = idx >> 6;         // 64 rows per sample
    const int j    = idx & 63;
    const int tid  = threadIdx.x;
    const int w    = tid >> 6;         // wave 0..3
    const int lane = tid & 63;         // float4 column chunk (D=256 -> 64)

    const int ml  = text_len[b] - 2;   // min_len in [1, 63]
    const int len = lengths[b];

    float4 a0 = make_float4(0.f, 0.f, 0.f, 0.f);
    float4 a1 = a0, a2 = a0, a3 = a0;
    float inv = 0.f;

    if (j >= 1 && j <= ml) {
        const unsigned ps = ((unsigned)(len + ml - 1)) / (unsigned)ml;
        inv = 1.0f / (float)ps;
        const int lo = (j - 1) * (int)ps;
        int hi = j * (int)ps;
        if (hi > len) hi = len;

        const float4* __restrict__ xb =
            (const float4*)(x + (size_t)b * (size_t)T * D_AV);

        // wave w covers rows lo+w, lo+w+4, ... ; 4 independent accumulators
        int t = lo + w;
        for (; t + 12 < hi; t += 16) {
            float4 v0 = xb[(size_t)(t     ) * 64 + lane];
            float4 v1 = xb[(size_t)(t +  4) * 64 + lane];
            float4 v2 = xb[(size_t)(t +  8) * 64 + lane];
            float4 v3 = xb[(size_t)(t + 12) * 64 + lane];
            a0.x += v0.x; a0.y += v0.y; a0.z += v0.z; a0.w += v0.w;
            a1.x += v1.x; a1.y += v1.y; a1.z += v1.z; a1.w += v1.w;
            a2.x += v2.x; a2.y += v2.y; a2.z += v2.z; a2.w += v2.w;
            a3.x += v3.x; a3.y += v3.y; a3.z += v3.z; a3.w += v3.w;
        }
        for (; t < hi; t += 4) {
            float4 v = xb[(size_t)t * 64 + lane];
            a0.x += v.x; a0.y += v.y; a0.z += v.z; a0.w += v.w;
        }
        a0.x += a1.x + a2.x + a3.x;
        a0.y += a1.y + a2.y + a3.y;
        a0.z += a1.z + a2.z + a3.z;
        a0.w += a1.w + a2.w + a3.w;
    }

    __shared__ float4 red[4][64];
    red[w][lane] = a0;
    __syncthreads();
    if (tid < 64) {
        float4 r0 = red[0][tid], r1 = red[1][tid],
               r2 = red[2][tid], r3 = red[3][tid];
        float4 s;
        s.x = (r0.x + r1.x + r2.x + r3.x) * inv;
        s.y = (r0.y + r1.y + r2.y + r3.y) * inv;
        s.z = (r0.z + r1.z + r2.z + r3.z) * inv;
        s.w = (r0.w + r1.w + r2.w + r3.w) * inv;
        // rows outside [1, ml]: inv==0 and acc==0 -> exact zeros
        float4* __restrict__ orow =
            (float4*)(out + ((size_t)b * DST_LEN + j) * D_AV);
        orow[tid] = s;
    }
}

__global__ __launch_bounds__(256)
void fused_align_kernel(const float4* __restrict__ text_in,
                        float4* __restrict__ text_out,
                        const float* __restrict__ audio_x,
                        const float* __restrict__ video_x,
                        const int* __restrict__ text_lengths,
                        const int* __restrict__ audio_lengths,
                        const int* __restrict__ video_lengths,
                        float* __restrict__ out_audio,
                        float* __restrict__ out_video) {
    const int blk = blockIdx.x;
    if (blk < NB_COPY) {
        // text passthrough: 1024 float4 per block
        const int base = blk * 1024 + threadIdx.x;
        #pragma unroll
        for (int k = 0; k < 4; ++k)
            text_out[base + k * 256] = text_in[base + k * 256];
    } else if (blk < NB_COPY + BATCH * DST_LEN) {
        align_row(audio_x, text_lengths, audio_lengths, out_audio,
                  SEQ_A, blk - NB_COPY);
    } else {
        align_row(video_x, text_lengths, video_lengths, out_video,
                  SEQ_V, blk - NB_COPY - BATCH * DST_LEN);
    }
}

extern "C" void kernel_launch(void* const* d_in, const int* in_sizes, int n_in,
                              void* d_out, int out_size, void* d_ws, size_t ws_size,
                              hipStream_t stream) {
    const float* text_x  = (const float*)d_in[0];
    const float* audio_x = (const float*)d_in[1];
    const float* video_x = (const float*)d_in[2];
    const int* text_lengths  = (const int*)d_in[3];
    const int* audio_lengths = (const int*)d_in[4];
    const int* video_lengths = (const int*)d_in[5];

    float* out = (float*)d_out;
    float* out_text  = out;                                        // B*64*768
    float* out_audio = out_text  + (size_t)BATCH * SEQ_T * D_T;    // B*64*256
    float* out_video = out_audio + (size_t)BATCH * DST_LEN * D_AV; // B*64*256

    const int blocks = NB_COPY + 2 * BATCH * DST_LEN;              // 17,920
    fused_align_kernel<<<blocks, 256, 0, stream>>>(
        (const float4*)text_x, (float4*)out_text,
        audio_x, video_x,
        text_lengths, audio_lengths, video_lengths,
        out_audio, out_video);
}